// Round 6
// baseline (87636.926 us; speedup 1.0000x reference)
//
#include <hip/hip_runtime.h>
#include <math.h>

#define NL 10
#define C 128
#define CS 256
#define NV 256
#define NB 32
#define TT 1024
#define CH_BYTES 131072

// ---------------- K1: embedding lookup ------------------------------------------
__global__ __launch_bounds__(256) void k_embed(const int* __restrict__ prompt,
                                               const float* __restrict__ E,
                                               float* __restrict__ X) {
  int idx = blockIdx.x * 256 + threadIdx.x;
  const float4* E4 = (const float4*)E;
  float4* X4 = (float4*)X;
#pragma unroll
  for (int p = 0; p < 4; ++p) {
    int i = idx + p * 262144;
    int row = i >> 5, c4 = i & 31;
    int tk = prompt[row];
    X4[i] = E4[tk * 32 + c4];
  }
}

// ---------------- K1b: de-interleave Wf/Wg taps (L*C*C = 163840 elems/tap) -------
__global__ __launch_bounds__(256) void k_deint(const float* __restrict__ Wf,
                                               const float* __restrict__ Wg,
                                               float* __restrict__ Wf0c,
                                               float* __restrict__ Wf1c,
                                               float* __restrict__ Wg0c,
                                               float* __restrict__ Wg1c) {
  int i = blockIdx.x * 256 + threadIdx.x;  // < 163840
  float2 f = *(const float2*)(Wf + 2 * (size_t)i);
  float2 g = *(const float2*)(Wg + 2 * (size_t)i);
  Wf0c[i] = f.x; Wf1c[i] = f.y; Wg0c[i] = g.x; Wg1c[i] = g.y;
}

// ---------------- K2: one dilated residual layer over full prompt ----------------
__global__ __launch_bounds__(256) void k_layer(
    const float* __restrict__ Xin, float* __restrict__ Xout,
    const float* __restrict__ Wf, const float* __restrict__ Wg,
    const float* __restrict__ bf, const float* __restrict__ bg,
    const float* __restrict__ Wres, const float* __restrict__ bres,
    float* __restrict__ rings, float* __restrict__ zlast, int l) {
  const int tid = threadIdx.x;
  const int m = blockIdx.x;
  const int b = m >> 3;
  const int t0 = (m & 7) << 7;
  const int d = 1 << l;

  __shared__ __align__(16) float sm[12416];
  float* Axd = sm;
  float* Ax  = sm + 16 * 132;
  float* Wfs = sm + 32 * 132;
  float* Wgs = Wfs + 16 * 256;

  const int rg = tid >> 4, cg = tid & 15;

  float af[8][8] = {};
  float ag[8][8] = {};

  for (int kc = 0; kc < 8; ++kc) {
    __syncthreads();
#pragma unroll
    for (int p = 0; p < 2; ++p) {
      int li = tid + p * 256;
      int row = li >> 2, c4 = li & 3;
      int ci = kc * 16 + c4 * 4;
      int t = t0 + row;
      float4 vx = *(const float4*)(Xin + ((size_t)b * TT + t) * C + ci);
      float4 vd = make_float4(0.f, 0.f, 0.f, 0.f);
      int ts = t - d;
      if (ts >= 0) vd = *(const float4*)(Xin + ((size_t)b * TT + ts) * C + ci);
      Ax[(c4 * 4 + 0) * 132 + row] = vx.x;
      Ax[(c4 * 4 + 1) * 132 + row] = vx.y;
      Ax[(c4 * 4 + 2) * 132 + row] = vx.z;
      Ax[(c4 * 4 + 3) * 132 + row] = vx.w;
      Axd[(c4 * 4 + 0) * 132 + row] = vd.x;
      Axd[(c4 * 4 + 1) * 132 + row] = vd.y;
      Axd[(c4 * 4 + 2) * 132 + row] = vd.z;
      Axd[(c4 * 4 + 3) * 132 + row] = vd.w;
    }
#pragma unroll
    for (int p = 0; p < 4; ++p) {
      int li = tid + p * 256;
      int ci = li >> 6, cc = (li & 63) << 2;
      size_t off = ((size_t)(l * C + kc * 16 + ci) * C) * 2 + cc;
      *(float4*)&Wfs[ci * 256 + cc] = *(const float4*)(Wf + off);
      *(float4*)&Wgs[ci * 256 + cc] = *(const float4*)(Wg + off);
    }
    __syncthreads();
    for (int ci = 0; ci < 16; ++ci) {
      float4 d0 = *(float4*)&Axd[ci * 132 + rg * 8];
      float4 d1 = *(float4*)&Axd[ci * 132 + rg * 8 + 4];
      float4 x0 = *(float4*)&Ax[ci * 132 + rg * 8];
      float4 x1 = *(float4*)&Ax[ci * 132 + rg * 8 + 4];
      float axd[8] = {d0.x, d0.y, d0.z, d0.w, d1.x, d1.y, d1.z, d1.w};
      float ax[8]  = {x0.x, x0.y, x0.z, x0.w, x1.x, x1.y, x1.z, x1.w};
#pragma unroll
      for (int jj = 0; jj < 4; ++jj) {
        float4 wf = *(float4*)&Wfs[ci * 256 + cg * 16 + jj * 4];
        float4 wg = *(float4*)&Wgs[ci * 256 + cg * 16 + jj * 4];
#pragma unroll
        for (int i = 0; i < 8; ++i) {
          af[i][2 * jj]     += axd[i] * wf.x + ax[i] * wf.y;
          af[i][2 * jj + 1] += axd[i] * wf.z + ax[i] * wf.w;
          ag[i][2 * jj]     += axd[i] * wg.x + ax[i] * wg.y;
          ag[i][2 * jj + 1] += axd[i] * wg.z + ax[i] * wg.w;
        }
      }
    }
  }

  float bfv[8], bgv[8];
#pragma unroll
  for (int j = 0; j < 8; ++j) {
    bfv[j] = bf[l * C + cg * 8 + j];
    bgv[j] = bg[l * C + cg * 8 + j];
  }
#pragma unroll
  for (int i = 0; i < 8; ++i)
#pragma unroll
    for (int j = 0; j < 8; ++j) {
      float fv = tanhf(af[i][j] + bfv[j]);
      float gv = 1.f / (1.f + expf(-(ag[i][j] + bgv[j])));
      af[i][j] = fv * gv;
    }
  if (((m & 7) == 7) && rg == 15) {
#pragma unroll
    for (int j = 0; j < 8; ++j)
      zlast[((size_t)l * NB + b) * C + cg * 8 + j] = af[7][j];
  }
#pragma unroll
  for (int i = 0; i < 8; ++i)
#pragma unroll
    for (int j = 0; j < 8; ++j) ag[i][j] = 0.f;

  float* zs  = sm;
  float* Wrs = sm + 32 * 132;
  for (int c = 0; c < 4; ++c) {
    __syncthreads();
    if ((cg >> 2) == c) {
      int kl = (cg & 3) * 8;
#pragma unroll
      for (int i = 0; i < 8; ++i)
#pragma unroll
        for (int j = 0; j < 8; ++j) zs[(kl + j) * 132 + rg * 8 + i] = af[i][j];
    }
#pragma unroll
    for (int p = 0; p < 4; ++p) {
      int li = tid + p * 256;
      int kr = li >> 5, cc = (li & 31) << 2;
      *(float4*)&Wrs[kr * 128 + cc] =
          *(const float4*)(Wres + ((size_t)(l * C + c * 32 + kr)) * C + cc);
    }
    __syncthreads();
    for (int k = 0; k < 32; ++k) {
      float4 a0 = *(float4*)&zs[k * 132 + rg * 8];
      float4 a1 = *(float4*)&zs[k * 132 + rg * 8 + 4];
      float4 w0 = *(float4*)&Wrs[k * 128 + cg * 8];
      float4 w1 = *(float4*)&Wrs[k * 128 + cg * 8 + 4];
      float a[8] = {a0.x, a0.y, a0.z, a0.w, a1.x, a1.y, a1.z, a1.w};
      float wv[8] = {w0.x, w0.y, w0.z, w0.w, w1.x, w1.y, w1.z, w1.w};
#pragma unroll
      for (int i = 0; i < 8; ++i)
#pragma unroll
        for (int j = 0; j < 8; ++j) ag[i][j] += a[i] * wv[j];
    }
  }

  float brv[8];
#pragma unroll
  for (int j = 0; j < 8; ++j) brv[j] = bres[l * C + cg * 8 + j];
#pragma unroll
  for (int i = 0; i < 8; ++i) {
    int t = t0 + rg * 8 + i;
    const float4* xi = (const float4*)(Xin + ((size_t)b * TT + t) * C + cg * 8);
    float4 v0 = xi[0], v1 = xi[1];
    float o[8] = {v0.x, v0.y, v0.z, v0.w, v1.x, v1.y, v1.z, v1.w};
#pragma unroll
    for (int j = 0; j < 8; ++j) o[j] += brv[j] + ag[i][j];
    float4* xo = (float4*)(Xout + ((size_t)b * TT + t) * C + cg * 8);
    xo[0] = make_float4(o[0], o[1], o[2], o[3]);
    xo[1] = make_float4(o[4], o[5], o[6], o[7]);
    if (t >= TT - d) {
      int slot = t - (TT - d);
      float* rp = rings + (size_t)(d - 1) * NB * C + ((size_t)slot * NB + b) * C + cg * 8;
      *(float4*)&rp[0] = v0;
      *(float4*)&rp[4] = v1;
    }
  }
}

// ---------------- K3: skips@T-1 + head -> tok0 -----------------------------------
__global__ __launch_bounds__(256) void k_head0(
    const float* __restrict__ zlast, const float* __restrict__ Wskip,
    const float* __restrict__ bskip, const float* __restrict__ Wo1,
    const float* __restrict__ bo1, const float* __restrict__ Wo2,
    const float* __restrict__ bo2, char* __restrict__ chst,
    int* __restrict__ dout, int ostride) {
  int b = blockIdx.x, tid = threadIdx.x;
  __shared__ float zl[NL][C];
  __shared__ float sr[CS];
  __shared__ float h1[CS];
  __shared__ float lg[NV];
#pragma unroll
  for (int p = 0; p < 5; ++p) {
    int li = tid + p * 256;
    zl[li >> 7][li & 127] = zlast[((size_t)(li >> 7) * NB + b) * C + (li & 127)];
  }
  __syncthreads();
  float s = 0.f;
  for (int l = 0; l < NL; ++l) {
    s += bskip[l * CS + tid];
    const float* wp = Wskip + (size_t)(l * C) * CS + tid;
    for (int k = 0; k < C; ++k) s += zl[l][k] * wp[(size_t)k * CS];
  }
  sr[tid] = fmaxf(s, 0.f);
  __syncthreads();
  float h = bo1[tid];
  {
    const float* wp = Wo1 + tid;
    for (int k = 0; k < CS; ++k) h += sr[k] * wp[(size_t)k * CS];
  }
  h1[tid] = fmaxf(h, 0.f);
  __syncthreads();
  float lv = bo2[tid];
  {
    const float* wp = Wo2 + tid;
    for (int k = 0; k < CS; ++k) lv += h1[k] * wp[(size_t)k * NV];
  }
  lg[tid] = lv;
  __syncthreads();
  if (tid == 0) {
    float bv = lg[0]; int bi = 0;
    for (int v = 1; v < NV; ++v)
      if (lg[v] > bv) { bv = lg[v]; bi = v; }
    *(unsigned*)(chst + (size_t)b * CH_BYTES) = (unsigned)bi;
    dout[(size_t)b * ostride + TT] = bi;
  }
}

// ---------------- K4: copy prompt into output ------------------------------------
__global__ __launch_bounds__(256) void k_copyprompt(const int* __restrict__ prompt,
                                                    int* __restrict__ dout,
                                                    int ostride) {
  int idx = blockIdx.x * 256 + threadIdx.x;
  int b = idx >> 10, t = idx & 1023;
  dout[(size_t)b * ostride + t] = prompt[idx];
}

// ---------------- K5: persistent decode — ONE self-contained WG per chain --------
// 32 WGs x 512 threads. Everything local: past-dots, x-dots, Wres, skips, head,
// argmax, ring update. NO cross-WG communication (plain loads/stores + barriers).
// Weight stream/step = ~5.0 MB through one CU's L1 -> predicted ~35-40 us/step.
__global__ __launch_bounds__(512) void k_decode(
    const float* __restrict__ E,
    const float* __restrict__ Wf1c, const float* __restrict__ Wg1c,
    const float* __restrict__ Wf0c, const float* __restrict__ Wg0c,
    const float* __restrict__ bf, const float* __restrict__ bg,
    const float* __restrict__ Wres, const float* __restrict__ bres,
    const float* __restrict__ Wskip, const float* __restrict__ bskip,
    const float* __restrict__ Wo1, const float* __restrict__ bo1,
    const float* __restrict__ Wo2, const float* __restrict__ bo2,
    float* __restrict__ rings, char* __restrict__ chst,
    int* __restrict__ dout, int ostride) {
  const int tid = threadIdx.x;
  const int chain = blockIdx.x;
  const int nsteps = ostride - TT;

  __shared__ __align__(16) float SM[11008];
  __shared__ unsigned tokS;
  float* REDF = SM;             // [16][132]; head reuse [8][260]
  float* REDG = SM + 2112;      // [16][132]
  float* XX   = SM + 4224;      // [128]
  float* ZSH  = SM + 4352;      // [128]
  float* PAST = SM + 4480;      // [10][128]
  float* SK   = SM + 5760;      // [256]
  float* H1F  = SM + 6016;      // [256]
  float* LGT  = SM + 6272;      // [256]
  float* BRES = SM + 6528;      // [9][128]
  float* BSUM = SM + 7680;      // [256]
  float* BO1  = SM + 7936;      // [256]
  float* BO2  = SM + 8192;      // [256]
  float* BFL  = SM + 8448;      // [10][128]
  float* BGL  = SM + 9728;      // [10][128]

  // bias preloads
  for (int li = tid; li < 9 * C; li += 512) BRES[li] = bres[li];
  for (int li = tid; li < NL * C; li += 512) { BFL[li] = bf[li]; BGL[li] = bg[li]; }
  if (tid < CS) {
    float sacc = 0.f;
    for (int l = 0; l < NL; ++l) sacc += bskip[l * CS + tid];
    BSUM[tid] = sacc;
    BO1[tid] = bo1[tid];
    BO2[tid] = bo2[tid];
  }
  unsigned tok = *(const unsigned*)(chst + (size_t)chain * CH_BYTES);
  __syncthreads();

  const int j4 = tid & 31, ks = tid >> 5;      // 128-out matvecs: 32 quads x 16-way K
  const int j4b = tid & 63, ksb = tid >> 6;    // 256-out matvecs: 64 quads x 8-way K

  for (int s = 0; s < nsteps - 1; ++s) {
    // x = E[tok]; all 10 past rows (plain loads; same WG wrote them)
    if (tid < C) XX[tid] = E[(size_t)tok * C + tid];
    for (int p = 0; p < 3; ++p) {
      int li = tid + p * 512;
      if (li < NL * C) {
        int l = li >> 7, cc = li & 127;
        int D = 1 << l, slo = s & (D - 1);
        PAST[l * 128 + cc] =
            rings[(size_t)(D - 1) * NB * C + ((size_t)slo * NB + chain) * C + cc];
      }
    }
    float4 skacc = make_float4(0.f, 0.f, 0.f, 0.f);
    __syncthreads();

#pragma unroll
    for (int l = 0; l < NL; ++l) {
      // phase A: fused fg dot (past-tap + x-tap), prefetch Wres into regs
      const float4* wf0 = (const float4*)(Wf0c + (size_t)l * C * C) + (8 * ks) * 32 + j4;
      const float4* wf1 = (const float4*)(Wf1c + (size_t)l * C * C) + (8 * ks) * 32 + j4;
      const float4* wg0 = (const float4*)(Wg0c + (size_t)l * C * C) + (8 * ks) * 32 + j4;
      const float4* wg1 = (const float4*)(Wg1c + (size_t)l * C * C) + (8 * ks) * 32 + j4;
      const float4* wrp = (const float4*)(Wres + (size_t)l * C * C) + (8 * ks) * 32 + j4;
      float4 aF = make_float4(0, 0, 0, 0), aG = make_float4(0, 0, 0, 0);
      float4 wrv[8];
#pragma unroll
      for (int kk = 0; kk < 8; ++kk) {
        float pv = PAST[l * 128 + 8 * ks + kk];
        float xv = XX[8 * ks + kk];
        float4 a = wf0[kk * 32], bq = wf1[kk * 32];
        float4 cq = wg0[kk * 32], dq = wg1[kk * 32];
        if (l < 9) wrv[kk] = wrp[kk * 32];
        aF.x += pv * a.x + xv * bq.x; aF.y += pv * a.y + xv * bq.y;
        aF.z += pv * a.z + xv * bq.z; aF.w += pv * a.w + xv * bq.w;
        aG.x += pv * cq.x + xv * dq.x; aG.y += pv * cq.y + xv * dq.y;
        aG.z += pv * cq.z + xv * dq.z; aG.w += pv * cq.w + xv * dq.w;
      }
      *(float4*)&REDF[ks * 132 + 4 * j4] = aF;
      *(float4*)&REDG[ks * 132 + 4 * j4] = aG;
      __syncthreads();
      // phase B: z-reduce + ring write (pre-update x)
      if (tid < C) {
        float F = BFL[l * C + tid], G = BGL[l * C + tid];
#pragma unroll
        for (int r = 0; r < 16; ++r) { F += REDF[r * 132 + tid]; G += REDG[r * 132 + tid]; }
        ZSH[tid] = tanhf(F) * (1.f / (1.f + expf(-G)));
        int D = 1 << l, slo = s & (D - 1);
        rings[(size_t)(D - 1) * NB * C + ((size_t)slo * NB + chain) * C + tid] = XX[tid];
      }
      __syncthreads();
      // phase C: skip partial (registers) + Wres partial
      {
        const float4* Ws4 = (const float4*)(Wskip + (size_t)l * C * CS);
#pragma unroll
        for (int kk = 0; kk < 16; ++kk) {
          float zv = ZSH[16 * ksb + kk];
          float4 w = Ws4[(size_t)(16 * ksb + kk) * 64 + j4b];
          skacc.x += zv * w.x; skacc.y += zv * w.y;
          skacc.z += zv * w.z; skacc.w += zv * w.w;
        }
      }
      if (l < 9) {
        float4 aR = make_float4(0, 0, 0, 0);
#pragma unroll
        for (int kk = 0; kk < 8; ++kk) {
          float zv = ZSH[8 * ks + kk];
          aR.x += zv * wrv[kk].x; aR.y += zv * wrv[kk].y;
          aR.z += zv * wrv[kk].z; aR.w += zv * wrv[kk].w;
        }
        *(float4*)&REDF[ks * 132 + 4 * j4] = aR;
        __syncthreads();
        // phase D: x update
        if (tid < C) {
          float v = BRES[l * C + tid];
#pragma unroll
          for (int r = 0; r < 16; ++r) v += REDF[r * 132 + tid];
          XX[tid] += v;
        }
        __syncthreads();
      }
    }

    // ---- head (all local) ----
    __syncthreads();  // REDF free (last layer had no D phase)
    *(float4*)&REDF[ksb * 260 + 4 * j4b] = skacc;
    __syncthreads();
    if (tid < CS) {
      float v = BSUM[tid];
#pragma unroll
      for (int r = 0; r < 8; ++r) v += REDF[r * 260 + tid];
      SK[tid] = fmaxf(v, 0.f);
    }
    __syncthreads();
    {
      float4 aH = make_float4(0, 0, 0, 0);
#pragma unroll
      for (int kk = 0; kk < 32; ++kk) {
        float sv = SK[32 * ksb + kk];
        float4 w = *((const float4*)Wo1 + (size_t)(32 * ksb + kk) * 64 + j4b);
        aH.x += sv * w.x; aH.y += sv * w.y; aH.z += sv * w.z; aH.w += sv * w.w;
      }
      *(float4*)&REDF[ksb * 260 + 4 * j4b] = aH;
    }
    __syncthreads();
    if (tid < CS) {
      float v = BO1[tid];
#pragma unroll
      for (int r = 0; r < 8; ++r) v += REDF[r * 260 + tid];
      H1F[tid] = fmaxf(v, 0.f);
    }
    __syncthreads();
    {
      float4 aL = make_float4(0, 0, 0, 0);
#pragma unroll
      for (int kk = 0; kk < 32; ++kk) {
        float hv = H1F[32 * ksb + kk];
        float4 w = *((const float4*)Wo2 + (size_t)(32 * ksb + kk) * 64 + j4b);
        aL.x += hv * w.x; aL.y += hv * w.y; aL.z += hv * w.z; aL.w += hv * w.w;
      }
      *(float4*)&REDF[ksb * 260 + 4 * j4b] = aL;
    }
    __syncthreads();
    if (tid < CS) {
      float v = BO2[tid];
#pragma unroll
      for (int r = 0; r < 8; ++r) v += REDF[r * 260 + tid];
      LGT[tid] = v;
    }
    __syncthreads();
    if (tid < 64) {
      float bv = LGT[4 * tid]; int bi = 4 * tid;
#pragma unroll
      for (int q = 1; q < 4; ++q) {
        float vq = LGT[4 * tid + q];
        if (vq > bv) { bv = vq; bi = 4 * tid + q; }
      }
#pragma unroll
      for (int off = 32; off >= 1; off >>= 1) {
        float ov = __shfl_down(bv, off);
        int oi = __shfl_down(bi, off);
        if (ov > bv || (ov == bv && oi < bi)) { bv = ov; bi = oi; }
      }
      if (tid == 0) {
        tokS = (unsigned)bi;
        dout[(size_t)chain * ostride + TT + 1 + s] = bi;
      }
    }
    __syncthreads();
    tok = tokS;
    __syncthreads();
  }
}

// ---------------- host launcher ---------------------------------------------------
extern "C" void kernel_launch(void* const* d_in, const int* in_sizes, int n_in,
                              void* d_out, int out_size, void* d_ws, size_t ws_size,
                              hipStream_t stream) {
  const int* prompt = (const int*)d_in[0];
  const float* E    = (const float*)d_in[2];
  const float* Wf   = (const float*)d_in[3];
  const float* Wg   = (const float*)d_in[4];
  const float* bf   = (const float*)d_in[5];
  const float* bg   = (const float*)d_in[6];
  const float* Wres = (const float*)d_in[7];
  const float* bres = (const float*)d_in[8];
  const float* Wskip= (const float*)d_in[9];
  const float* bskip= (const float*)d_in[10];
  const float* Wo1  = (const float*)d_in[11];
  const float* bo1  = (const float*)d_in[12];
  const float* Wo2  = (const float*)d_in[13];
  const float* bo2  = (const float*)d_in[14];
  int* dout = (int*)d_out;
  int ostride = out_size / NB;

  char* ws = (char*)d_ws;
  float* X0    = (float*)ws;                    // 16,777,216 B (reused for deint W)
  float* X1    = (float*)(ws + 16777216);       // 16,777,216 B
  float* rings = (float*)(ws + 33554432);       // 16,760,832 B (sum(d)*32*128 f32)
  float* zlast = (float*)(ws + 50315264);       // 163,840 B
  char* chst   = ws + 50479104;                 // 4,194,304 B
  // deinterleaved taps live in X0's region (dead after the prompt layers):
  float* Wf0c  = (float*)ws;                    // 163,840 floats each
  float* Wf1c  = Wf0c + 163840;
  float* Wg0c  = Wf1c + 163840;
  float* Wg1c  = Wg0c + 163840;

  k_embed<<<1024, 256, 0, stream>>>(prompt, E, X0);
  float* xa = X0;
  float* xb = X1;
  for (int l = 0; l < NL; ++l) {
    k_layer<<<256, 256, 0, stream>>>(xa, xb, Wf, Wg, bf, bg, Wres, bres, rings, zlast, l);
    float* t = xa; xa = xb; xb = t;
  }
  k_head0<<<NB, 256, 0, stream>>>(zlast, Wskip, bskip, Wo1, bo1, Wo2, bo2, chst, dout, ostride);
  k_copyprompt<<<128, 256, 0, stream>>>(prompt, dout, ostride);
  k_deint<<<640, 256, 0, stream>>>(Wf, Wg, Wf0c, Wf1c, Wg0c, Wg1c);
  k_decode<<<NB, 512, 0, stream>>>(E, Wf1c, Wg1c, Wf0c, Wg0c, bf, bg, Wres, bres,
                                   Wskip, bskip, Wo1, bo1, Wo2, bo2, rings, chst,
                                   dout, ostride);
}